// Round 13
// baseline (533.636 us; speedup 1.0000x reference)
//
#include <hip/hip_runtime.h>
#include <hip/hip_bf16.h>
#include <math.h>

// ---------------------------------------------------------------------------
// MultiScaleGNN: 3x GAT (single head) -> BiLSTM JK attention -> linear out
// GAT: CSR (built once) + per-dst aggregation, 4 edges in flight, no atomics.
// LSTM: bf16 MFMA; weights LDS-resident; 768 thr / 12 waves; occupancy pinned
// to EXACTLY 3 waves/EU via amdgpu_waves_per_eu(3,3) -> 170-reg budget, no
// spill (one-arg/min-only forms let the allocator target 6/EU = 84 regs and
// spill: r6/r10/r11). Wave-persistent interleaved 16-node tiles; logits in
// registers -> global; jk_kernel epilogue.
// ---------------------------------------------------------------------------

typedef __attribute__((ext_vector_type(4))) float f32x4;
typedef __attribute__((ext_vector_type(8))) short bf16x8;

__device__ __forceinline__ float rcp_f(float x) {
    return __builtin_amdgcn_rcpf(x);          // raw v_rcp_f32, ~1 ulp
}
__device__ __forceinline__ float sigmoid_f(float x) {
    return rcp_f(1.0f + __expf(-x));
}
__device__ __forceinline__ float tanh_f(float x) {
    return fmaf(2.0f, rcp_f(1.0f + __expf(-2.0f * x)), -1.0f);
}
__device__ __forceinline__ unsigned short f2bf(float x) {   // RNE f32->bf16
    union { float f; unsigned int u; } v; v.f = x;
    unsigned int r = (v.u + 0x7FFFu + ((v.u >> 16) & 1u)) >> 16;
    return (unsigned short)r;
}
__device__ __forceinline__ float bf2f(unsigned short u) {
    union { unsigned int i; float f; } v; v.i = ((unsigned int)u) << 16;
    return v.f;
}

// ---- GAT: h = x @ W^T (bf16 out); al = h @ asrc ; ar = h @ adst -----------
template<int K>
__global__ __launch_bounds__(256) void lin_kernel(
    const float* __restrict__ x, const float* __restrict__ W,
    const float* __restrict__ asrc, const float* __restrict__ adst,
    unsigned short* __restrict__ h, float* __restrict__ al,
    float* __restrict__ ar, int N)
{
    __shared__ __align__(16) float Wl[64][K + 4];
    for (int i = threadIdx.x; i < 64 * K; i += 256)
        Wl[i / K][i % K] = W[i];
    __syncthreads();

    int lane = threadIdx.x & 63;
    float as = asrc[lane], ad = adst[lane];
    int wid = (blockIdx.x * 256 + threadIdx.x) >> 6;
    int nw  = (gridDim.x * 256) >> 6;
    int n4max = (N + 3) >> 2;
    for (int n4 = wid; n4 < n4max; n4 += nw) {
        int nb = __builtin_amdgcn_readfirstlane(n4) << 2;
        const float* xr0 = x + (size_t)nb * K;
        const float* xr1 = x + (size_t)min(nb + 1, N - 1) * K;
        const float* xr2 = x + (size_t)min(nb + 2, N - 1) * K;
        const float* xr3 = x + (size_t)min(nb + 3, N - 1) * K;
        float a0 = 0.f, a1 = 0.f, a2 = 0.f, a3 = 0.f;
        #pragma unroll 4
        for (int k = 0; k < K; k += 4) {
            f32x4 wv = *reinterpret_cast<const f32x4*>(&Wl[lane][k]);
            float4 x0 = *reinterpret_cast<const float4*>(xr0 + k);
            float4 x1 = *reinterpret_cast<const float4*>(xr1 + k);
            float4 x2 = *reinterpret_cast<const float4*>(xr2 + k);
            float4 x3 = *reinterpret_cast<const float4*>(xr3 + k);
            a0 += x0.x * wv.x + x0.y * wv.y + x0.z * wv.z + x0.w * wv.w;
            a1 += x1.x * wv.x + x1.y * wv.y + x1.z * wv.z + x1.w * wv.w;
            a2 += x2.x * wv.x + x2.y * wv.y + x2.z * wv.z + x2.w * wv.w;
            a3 += x3.x * wv.x + x3.y * wv.y + x3.z * wv.z + x3.w * wv.w;
        }
        float accs[4] = {a0, a1, a2, a3};
        #pragma unroll
        for (int j = 0; j < 4; ++j) {
            int n = nb + j;
            if (n >= N) break;
            float acc = accs[j];
            h[(size_t)n * 64 + lane] = f2bf(acc);
            float pa = acc * as, pr = acc * ad;
            #pragma unroll
            for (int off = 32; off > 0; off >>= 1) {
                pa += __shfl_down(pa, off);
                pr += __shfl_down(pr, off);
            }
            if (lane == 0) { al[n] = pa; ar[n] = pr; }
        }
    }
}

// ============================ CSR build (once) =============================
__global__ void csr_zero(int* __restrict__ deg, int* __restrict__ cursor, int N)
{
    int i = blockIdx.x * blockDim.x + threadIdx.x;
    if (i < N) { deg[i] = 0; cursor[i] = 0; }
}

__global__ void csr_hist(const int* __restrict__ dst, int* __restrict__ deg, int E)
{
    int i = blockIdx.x * blockDim.x + threadIdx.x;
    if (i < E) atomicAdd(&deg[dst[i]], 1);
}

__global__ void csr_scan1(const int* __restrict__ deg, int* __restrict__ incl,
                          int* __restrict__ part, int N)
{
    __shared__ int sb[2][256];
    int tid = threadIdx.x;
    int i = blockIdx.x * 256 + tid;
    int v = (i < N) ? deg[i] + 1 : 0;
    sb[0][tid] = v;
    __syncthreads();
    int cur = 0;
    #pragma unroll
    for (int off = 1; off < 256; off <<= 1) {
        int s = sb[cur][tid];
        if (tid >= off) s += sb[cur][tid - off];
        sb[cur ^ 1][tid] = s;
        cur ^= 1;
        __syncthreads();
    }
    if (i < N) incl[i] = sb[cur][tid];
    if (tid == 255) part[blockIdx.x] = sb[cur][255];
}

__global__ void csr_scan2(int* __restrict__ part, int NB)
{
    __shared__ int sb[2][256];
    int tid = threadIdx.x;
    int v = (tid < NB) ? part[tid] : 0;
    sb[0][tid] = v;
    __syncthreads();
    int cur = 0;
    #pragma unroll
    for (int off = 1; off < 256; off <<= 1) {
        int s = sb[cur][tid];
        if (tid >= off) s += sb[cur][tid - off];
        sb[cur ^ 1][tid] = s;
        cur ^= 1;
        __syncthreads();
    }
    if (tid < NB) part[tid] = sb[cur][tid] - v;   // exclusive
}

__global__ void csr_scan3(const int* __restrict__ deg, const int* __restrict__ incl,
                          const int* __restrict__ part, int* __restrict__ rowptr,
                          int N, int total)
{
    int i = blockIdx.x * blockDim.x + threadIdx.x;
    if (i < N)
        rowptr[i] = part[i >> 8] + incl[i] - (deg[i] + 1);
    if (i == 0) rowptr[N] = total;
}

__global__ void csr_scatter(const int* __restrict__ src, const int* __restrict__ dst,
                            const int* __restrict__ rowptr, int* __restrict__ cursor,
                            int* __restrict__ csr_src, int E, int N)
{
    int i = blockIdx.x * blockDim.x + threadIdx.x;
    if (i >= E + N) return;
    int s = (i < E) ? src[i] : (i - E);
    int d = (i < E) ? dst[i] : (i - E);
    int pos = atomicAdd(&cursor[d], 1);
    csr_src[rowptr[d] + pos] = s;
}

// ---- per-dst aggregation: softmax-weighted neighbor sum, fused finalize ----
// wave per dst; 4 edges/iter (16-lane groups), 4 channels/lane (8B loads).
// Dual output: f32 seq (next lin layer) + bf16 seq (LSTM A-frags + jk).
__global__ __launch_bounds__(256) void agg_kernel(
    const int* __restrict__ rowptr, const int* __restrict__ csr_src,
    const float* __restrict__ al, const float* __restrict__ ar,
    const unsigned short* __restrict__ h, const float* __restrict__ b,
    float* __restrict__ outseq, unsigned short* __restrict__ outseq_bf, int N)
{
    int lane = threadIdx.x & 63;
    int w = threadIdx.x >> 6;
    int d = blockIdx.x * 4 + w;
    if (d >= N) return;
    int li = lane & 15, grp = lane >> 4;      // grp 0..3, li = channel quad

    int rp0 = rowptr[d], rp1 = rowptr[d + 1];
    int degd = rp1 - rp0;
    float ard = ar[d];
    float den = 0.0f;
    float a0 = 0.f, a1 = 0.f, a2 = 0.f, a3 = 0.f;

    for (int c0 = 0; c0 < degd; c0 += 64) {
        int ne = min(64, degd - c0);
        int s_l = 0;
        float ex_l = 0.0f;                    // stays 0 for lane >= ne
        if (lane < ne) {
            s_l = csr_src[rp0 + c0 + lane];
            float e = al[s_l] + ard;
            e = (e >= 0.0f) ? e : 0.2f * e;
            ex_l = __expf(e);
        }
        float dsum = ex_l;
        #pragma unroll
        for (int off = 32; off > 0; off >>= 1) dsum += __shfl_xor(dsum, off);
        den += dsum;
        #pragma unroll 2
        for (int e2 = 0; e2 < ne; e2 += 4) {
            int eA = e2 + grp;
            float exb = __shfl(ex_l, eA);
            int sb = __shfl(s_l, eA);
            uint2 hv = *reinterpret_cast<const uint2*>(
                &h[(size_t)sb * 64 + li * 4]);
            a0 += exb * bf2f((unsigned short)(hv.x & 0xFFFFu));
            a1 += exb * bf2f((unsigned short)(hv.x >> 16));
            a2 += exb * bf2f((unsigned short)(hv.y & 0xFFFFu));
            a3 += exb * bf2f((unsigned short)(hv.y >> 16));
        }
    }
    #pragma unroll
    for (int off = 16; off < 64; off <<= 1) {
        a0 += __shfl_xor(a0, off);
        a1 += __shfl_xor(a1, off);
        a2 += __shfl_xor(a2, off);
        a3 += __shfl_xor(a3, off);
    }
    if (grp == 0) {
        float inv = rcp_f(den);
        int ch = li * 4;
        float4 v;
        v.x = fmaxf(fmaf(a0, inv, b[ch]),     0.0f);
        v.y = fmaxf(fmaf(a1, inv, b[ch + 1]), 0.0f);
        v.z = fmaxf(fmaf(a2, inv, b[ch + 2]), 0.0f);
        v.w = fmaxf(fmaf(a3, inv, b[ch + 3]), 0.0f);
        *reinterpret_cast<float4*>(&outseq[(size_t)d * 64 + ch]) = v;
        uint2 bb;
        bb.x = (unsigned int)f2bf(v.x) | ((unsigned int)f2bf(v.y) << 16);
        bb.y = (unsigned int)f2bf(v.z) | ((unsigned int)f2bf(v.w) << 16);
        *reinterpret_cast<uint2*>(&outseq_bf[(size_t)d * 64 + ch]) = bb;
    }
}

// ---- LSTM weight prep: bf16, FRAGMENT-LANE-MAJOR order --------------------
__global__ void prep_lstm(
    const float* __restrict__ WihF, const float* __restrict__ WhhF,
    const float* __restrict__ bihF, const float* __restrict__ bhhF,
    const float* __restrict__ WihB_, const float* __restrict__ WhhB_,
    const float* __restrict__ bihB_, const float* __restrict__ bhhB_,
    unsigned short* __restrict__ WB, float* __restrict__ bsum)
{
    int tid = blockIdx.x * blockDim.x + threadIdx.x;
    if (tid < 2 * 61440) {
        int dir = tid / 61440, rr = tid % 61440;
        const float* Wih = dir ? WihB_ : WihF;
        const float* Whh = dir ? WhhB_ : WhhF;
        float v;
        if (rr < 24576) {
            int f = rr >> 9, l = (rr >> 3) & 63, s = rr & 7;
            int kc = f & 1, qt = f >> 1;
            int q = qt / 6, t6 = qt % 6;
            int j = q * 96 + t6 * 16 + (l & 15);
            int k = kc * 32 + (l >> 4) * 8 + s;
            v = Wih[j * 64 + k];
        } else {
            int rr2 = rr - 24576;
            int f = rr2 >> 9, l = (rr2 >> 3) & 63, s = rr2 & 7;
            int kc = f % 3, qt = f / 3;
            int q = qt / 6, t6 = qt % 6;
            int j = q * 96 + t6 * 16 + (l & 15);
            int k = kc * 32 + (l >> 4) * 8 + s;
            v = Whh[j * 96 + k];
        }
        WB[tid] = f2bf(v);
    } else if (tid < 2 * 61440 + 2 * 384) {
        int q2 = tid - 2 * 61440;
        int dir = q2 / 384, j = q2 % 384;
        bsum[q2] = dir ? (bihB_[j] + bhhB_[j]) : (bihF[j] + bhhF[j]);
    }
}

// ---- BiLSTM recurrence (MFMA, LDS weights), logits -> global --------------
// 768 thr = 12 waves, grid 256. amdgpu_waves_per_eu(3,3) pins the register
// allocator to exactly 3 waves/EU (170-reg budget) -> no spill, 3 waves/SIMD.
// Wave (w,b) owns 16-node tiles {pass*3072 + w*256 + b}; pass 1 is a 53-tile
// tail. hs wave-private (16 rows, stride 104); logits in 24 regs, one global
// write at end. LDS = 120 KB weights + 39 KB hs = 159 KB.
__global__ __launch_bounds__(768) __attribute__((amdgpu_waves_per_eu(3, 3)))
void lstm_kernel(
    const unsigned short* __restrict__ seq_bf,
    const unsigned short* __restrict__ WB,
    const float* __restrict__ bsum, const float* __restrict__ attW,
    const float* __restrict__ attb, float* __restrict__ logitG, int N)
{
    __shared__ __align__(16) unsigned short smem[81408];
    unsigned short* WL = smem;                           // 61440 shorts

    const int tid  = threadIdx.x;
    const int lane = tid & 63;
    const int w    = tid >> 6;          // 0..11
    const int i16  = lane & 15;
    const int g    = lane >> 4;
    unsigned short* HSw = smem + 61440 + w * (16 * 104); // wave-private
    const int wglob = w * 256 + blockIdx.x;              // interleaved tiles
    const int tiles_total = (N + 15) >> 4;
    const float attb0 = attb[0];

    float la[24];
    #pragma unroll
    for (int a = 0; a < 24; ++a) la[a] = 0.0f;

    for (int dir = 0; dir < 2; ++dir) {
        __syncthreads();   // prev dir's WL reads complete
        {   // stage this dir's 120 KB of weight fragments (linear, b128)
            const f32x4* gsrc = reinterpret_cast<const f32x4*>(WB + dir * 61440);
            f32x4* ldst = reinterpret_cast<f32x4*>(WL);
            #pragma unroll
            for (int it = 0; it < 10; ++it)
                ldst[it * 768 + tid] = gsrc[it * 768 + tid];
        }
        const float* bs = bsum + dir * 384;
        const float* aw = attW + dir * 96;
        float bsr[24];
        #pragma unroll
        for (int t6 = 0; t6 < 6; ++t6)
            #pragma unroll
            for (int q = 0; q < 4; ++q)
                bsr[t6 * 4 + q] = bs[q * 96 + t6 * 16 + i16];
        float awr[6];
        #pragma unroll
        for (int t6 = 0; t6 < 6; ++t6) awr[t6] = aw[t6 * 16 + i16];
        __syncthreads();   // WL visible

        #pragma unroll
        for (int pass = 0; pass < 2; ++pass) {
            int tile = pass * 3072 + wglob;
            if (tile >= tiles_total) continue;

            // zero this wave's hs (cols 0..95 of 16 rows)
            for (int e2 = lane; e2 < 768; e2 += 64) {
                int r = e2 / 48, cdw = e2 % 48;
                *reinterpret_cast<unsigned int*>(&HSw[r * 104 + cdw * 2]) = 0u;
            }
            float c[24];
            #pragma unroll
            for (int a = 0; a < 24; ++a) c[a] = 0.0f;

            #pragma unroll
            for (int step = 0; step < 3; ++step) {
                int t = dir ? (2 - step) : step;
                int nn = tile * 16 + i16;
                nn = (nn < N) ? nn : (N - 1);
                const unsigned short* xr = seq_bf + ((size_t)t * N + nn) * 64 + g * 8;
                bf16x8 ax0 = *reinterpret_cast<const bf16x8*>(xr);
                bf16x8 ax1 = *reinterpret_cast<const bf16x8*>(xr + 32);
                const unsigned short* hrow = &HSw[i16 * 104];
                bf16x8 ah0 = *reinterpret_cast<const bf16x8*>(hrow + g * 8);
                bf16x8 ah1 = *reinterpret_cast<const bf16x8*>(hrow + 32 + g * 8);
                bf16x8 ah2 = *reinterpret_cast<const bf16x8*>(hrow + 64 + g * 8);
                const unsigned short* wbase = WL + lane * 8;

                float lp[4] = {0.0f, 0.0f, 0.0f, 0.0f};
                #pragma unroll
                for (int t6 = 0; t6 < 6; ++t6) {
                    const int jb = t6 * 16 + i16;
                    f32x4 acc4[4];
                    #pragma unroll
                    for (int q = 0; q < 4; ++q) {
                        float bv = bsr[t6 * 4 + q];
                        acc4[q] = (f32x4){bv, bv, bv, bv};
                    }
                    #pragma unroll
                    for (int q = 0; q < 4; ++q) {
                        const int qt = q * 6 + t6;
                        const unsigned short* wih = wbase + (qt * 2) * 512;
                        const unsigned short* whh = wbase + 24576 + (qt * 3) * 512;
                        acc4[q] = __builtin_amdgcn_mfma_f32_16x16x32_bf16(
                            ax0, *reinterpret_cast<const bf16x8*>(wih), acc4[q], 0, 0, 0);
                        acc4[q] = __builtin_amdgcn_mfma_f32_16x16x32_bf16(
                            ax1, *reinterpret_cast<const bf16x8*>(wih + 512), acc4[q], 0, 0, 0);
                        acc4[q] = __builtin_amdgcn_mfma_f32_16x16x32_bf16(
                            ah0, *reinterpret_cast<const bf16x8*>(whh), acc4[q], 0, 0, 0);
                        acc4[q] = __builtin_amdgcn_mfma_f32_16x16x32_bf16(
                            ah1, *reinterpret_cast<const bf16x8*>(whh + 512), acc4[q], 0, 0, 0);
                        acc4[q] = __builtin_amdgcn_mfma_f32_16x16x32_bf16(
                            ah2, *reinterpret_cast<const bf16x8*>(whh + 1024), acc4[q], 0, 0, 0);
                    }
                    #pragma unroll
                    for (int reg = 0; reg < 4; ++reg) {
                        float ii = acc4[0][reg];
                        float ff = acc4[1][reg];
                        float gg = acc4[2][reg];
                        float oo = acc4[3][reg];
                        float cn = sigmoid_f(ff) * c[t6 * 4 + reg]
                                 + sigmoid_f(ii) * tanh_f(gg);
                        c[t6 * 4 + reg] = cn;
                        float hn = sigmoid_f(oo) * tanh_f(cn);
                        HSw[(g * 4 + reg) * 104 + jb] = f2bf(hn);
                        lp[reg] += hn * awr[t6];
                    }
                }
                #pragma unroll
                for (int reg = 0; reg < 4; ++reg)
                    la[pass * 12 + t * 4 + reg] += lp[reg];
            }
        }
    }

    // write logits (sum over the 16 i16-lanes of each group, + bias)
    #pragma unroll
    for (int pass = 0; pass < 2; ++pass) {
        int tile = pass * 3072 + wglob;
        if (tile >= tiles_total) continue;
        #pragma unroll
        for (int t = 0; t < 3; ++t)
            #pragma unroll
            for (int reg = 0; reg < 4; ++reg) {
                float v = la[pass * 12 + t * 4 + reg];
                v += __shfl_xor(v, 1);
                v += __shfl_xor(v, 2);
                v += __shfl_xor(v, 4);
                v += __shfl_xor(v, 8);
                int n = tile * 16 + g * 4 + reg;
                if (i16 == 0 && n < N)
                    logitG[(size_t)t * N + n] = v + attb0;
            }
    }
}

// ---- JK epilogue: alpha = softmax(logits), agg = sum_t alpha*seq, out -----
// wave per node (grid-stride); shfl-broadcast 64-dot against outW in VGPRs.
__global__ __launch_bounds__(256) void jk_kernel(
    const float* __restrict__ logitG, const unsigned short* __restrict__ seq_bf,
    const float* __restrict__ outW, const float* __restrict__ outb,
    float* __restrict__ out, int N)
{
    int lane = threadIdx.x & 63;
    int w = threadIdx.x >> 6;

    f32x4 ow[16];
    #pragma unroll
    for (int kk = 0; kk < 16; ++kk)
        ow[kk] = *reinterpret_cast<const f32x4*>(&outW[(size_t)lane * 64 + kk * 4]);
    float ob = outb[lane];

    for (int n = blockIdx.x * 4 + w; n < N; n += gridDim.x * 4) {
        int nu = __builtin_amdgcn_readfirstlane(n);
        float l0 = logitG[nu], l1 = logitG[N + nu], l2 = logitG[2 * (size_t)N + nu];
        float mx = fmaxf(fmaxf(l0, l1), l2);
        float e0 = __expf(l0 - mx), e1 = __expf(l1 - mx), e2 = __expf(l2 - mx);
        float inv = rcp_f(e0 + e1 + e2);
        float a0 = e0 * inv, a1 = e1 * inv, a2 = e2 * inv;
        float aggk = a0 * bf2f(seq_bf[(size_t)nu * 64 + lane])
                   + a1 * bf2f(seq_bf[((size_t)N + nu) * 64 + lane])
                   + a2 * bf2f(seq_bf[((size_t)2 * N + nu) * 64 + lane]);
        float acc = ob;
        #pragma unroll
        for (int k = 0; k < 64; ++k) {
            float av = __shfl(aggk, k);
            float wv = (k & 3) == 0 ? ow[k >> 2].x :
                       (k & 3) == 1 ? ow[k >> 2].y :
                       (k & 3) == 2 ? ow[k >> 2].z : ow[k >> 2].w;
            acc = fmaf(av, wv, acc);
        }
        out[(size_t)nu * 64 + lane] = acc;
    }
}

// ---------------------------------------------------------------------------
extern "C" void kernel_launch(void* const* d_in, const int* in_sizes, int n_in,
                              void* d_out, int out_size, void* d_ws, size_t ws_size,
                              hipStream_t stream)
{
    const float* x    = (const float*)d_in[0];
    const int*   ei   = (const int*)d_in[1];
    const float* convW[3]  = {(const float*)d_in[2], (const float*)d_in[6],  (const float*)d_in[10]};
    const float* convAs[3] = {(const float*)d_in[3], (const float*)d_in[7],  (const float*)d_in[11]};
    const float* convAd[3] = {(const float*)d_in[4], (const float*)d_in[8],  (const float*)d_in[12]};
    const float* convB[3]  = {(const float*)d_in[5], (const float*)d_in[9],  (const float*)d_in[13]};
    const float* WihF = (const float*)d_in[14];
    const float* WhhF = (const float*)d_in[15];
    const float* bihF = (const float*)d_in[16];
    const float* bhhF = (const float*)d_in[17];
    const float* WihB = (const float*)d_in[18];
    const float* WhhB = (const float*)d_in[19];
    const float* bihB = (const float*)d_in[20];
    const float* bhhB = (const float*)d_in[21];
    const float* attW = (const float*)d_in[22];
    const float* attb = (const float*)d_in[23];
    const float* outW = (const float*)d_in[24];
    const float* outb = (const float*)d_in[25];

    int N = in_sizes[0] / 128;
    int E = in_sizes[1] / 2;
    const int* src = ei;
    const int* dst = ei + E;
    int total = E + N;

    float* w = (float*)d_ws;
    float* seq  = w;  w += (size_t)3 * N * 64;
    unsigned short* h_bf = (unsigned short*)w;  w += (size_t)N * 32;   // N*64 bf16
    float* al   = w;  w += N;
    float* ar   = w;  w += N;
    float* bsum = w;  w += 768;
    unsigned short* WB = (unsigned short*)w;  w += 61440;   // 122880 bf16
    unsigned short* seq_bf = (unsigned short*)w;  w += (size_t)3 * N * 32;  // bf16
    float* logitG = w;  w += (size_t)3 * N;
    int* deg     = (int*)w;        w += N;
    int* cursor  = (int*)w;        w += N;
    int* rowptr  = (int*)w;        w += (N + 1);
    int* incl    = (int*)w;        w += N;
    int* part    = (int*)w;        w += 256;
    int* csr_src = (int*)w;        w += total;

    int NB = (N + 255) / 256;

    // CSR build (graph is layer-invariant)
    csr_zero<<<NB, 256, 0, stream>>>(deg, cursor, N);
    csr_hist<<<(E + 255) / 256, 256, 0, stream>>>(dst, deg, E);
    csr_scan1<<<NB, 256, 0, stream>>>(deg, incl, part, N);
    csr_scan2<<<1, 256, 0, stream>>>(part, NB);
    csr_scan3<<<NB, 256, 0, stream>>>(deg, incl, part, rowptr, N, total);
    csr_scatter<<<(total + 255) / 256, 256, 0, stream>>>(src, dst, rowptr, cursor,
                                                         csr_src, E, N);

    prep_lstm<<<(2 * 61440 + 768 + 255) / 256, 256, 0, stream>>>(
        WihF, WhhF, bihF, bhhF, WihB, WhhB, bihB, bhhB, WB, bsum);

    for (int l = 0; l < 3; ++l) {
        const float* in = (l == 0) ? x : seq + (size_t)(l - 1) * N * 64;
        if (l == 0)
            lin_kernel<128><<<2048, 256, 0, stream>>>(in, convW[l], convAs[l], convAd[l],
                                                      h_bf, al, ar, N);
        else
            lin_kernel<64><<<2048, 256, 0, stream>>>(in, convW[l], convAs[l], convAd[l],
                                                     h_bf, al, ar, N);
        agg_kernel<<<(N + 3) / 4, 256, 0, stream>>>(rowptr, csr_src, al, ar, h_bf,
                                                    convB[l], seq + (size_t)l * N * 64,
                                                    seq_bf + (size_t)l * N * 64, N);
    }

    lstm_kernel<<<256, 768, 0, stream>>>(seq_bf, WB, bsum, attW, attb, logitG, N);
    jk_kernel<<<2048, 256, 0, stream>>>(logitG, seq_bf, outW, outb, (float*)d_out, N);
}

// Round 14
// 370.943 us; speedup vs baseline: 1.4386x; 1.4386x over previous
//
#include <hip/hip_runtime.h>
#include <hip/hip_bf16.h>
#include <math.h>

// ---------------------------------------------------------------------------
// MultiScaleGNN: 3x GAT (single head) -> BiLSTM JK attention -> linear out
// GAT: CSR (built once) + per-dst aggregation with 16-lane groups (4 dst per
// wave -> 4x fewer waves), no atomics.
// LSTM: bf16 MFMA; ALL weights LDS-resident; 512 thr / (512,2) -> VGPR 128,
// no spill (the ONLY empirically spill-free config for this body; all
// 768-thread variants collapse to 84 VGPR + spill: r6/r10/r11/r13).
// ---------------------------------------------------------------------------

typedef __attribute__((ext_vector_type(4))) float f32x4;
typedef __attribute__((ext_vector_type(8))) short bf16x8;

__device__ __forceinline__ float rcp_f(float x) {
    return __builtin_amdgcn_rcpf(x);          // raw v_rcp_f32, ~1 ulp
}
__device__ __forceinline__ float sigmoid_f(float x) {
    return rcp_f(1.0f + __expf(-x));
}
__device__ __forceinline__ float tanh_f(float x) {
    return fmaf(2.0f, rcp_f(1.0f + __expf(-2.0f * x)), -1.0f);
}
__device__ __forceinline__ unsigned short f2bf(float x) {   // RNE f32->bf16
    union { float f; unsigned int u; } v; v.f = x;
    unsigned int r = (v.u + 0x7FFFu + ((v.u >> 16) & 1u)) >> 16;
    return (unsigned short)r;
}
__device__ __forceinline__ float bf2f(unsigned short u) {
    union { unsigned int i; float f; } v; v.i = ((unsigned int)u) << 16;
    return v.f;
}

// ---- GAT: h = x @ W^T (bf16 out); al = h @ asrc ; ar = h @ adst -----------
// 4 nodes share each LDS W read (W is node-invariant) -> LDS traffic / 4.
template<int K>
__global__ __launch_bounds__(256) void lin_kernel(
    const float* __restrict__ x, const float* __restrict__ W,
    const float* __restrict__ asrc, const float* __restrict__ adst,
    unsigned short* __restrict__ h, float* __restrict__ al,
    float* __restrict__ ar, int N)
{
    __shared__ __align__(16) float Wl[64][K + 4];
    for (int i = threadIdx.x; i < 64 * K; i += 256)
        Wl[i / K][i % K] = W[i];
    __syncthreads();

    int lane = threadIdx.x & 63;
    float as = asrc[lane], ad = adst[lane];
    int wid = (blockIdx.x * 256 + threadIdx.x) >> 6;
    int nw  = (gridDim.x * 256) >> 6;
    int n4max = (N + 3) >> 2;
    for (int n4 = wid; n4 < n4max; n4 += nw) {
        int nb = __builtin_amdgcn_readfirstlane(n4) << 2;
        const float* xr0 = x + (size_t)nb * K;
        const float* xr1 = x + (size_t)min(nb + 1, N - 1) * K;
        const float* xr2 = x + (size_t)min(nb + 2, N - 1) * K;
        const float* xr3 = x + (size_t)min(nb + 3, N - 1) * K;
        float a0 = 0.f, a1 = 0.f, a2 = 0.f, a3 = 0.f;
        #pragma unroll 4
        for (int k = 0; k < K; k += 4) {
            f32x4 wv = *reinterpret_cast<const f32x4*>(&Wl[lane][k]);
            float4 x0 = *reinterpret_cast<const float4*>(xr0 + k);
            float4 x1 = *reinterpret_cast<const float4*>(xr1 + k);
            float4 x2 = *reinterpret_cast<const float4*>(xr2 + k);
            float4 x3 = *reinterpret_cast<const float4*>(xr3 + k);
            a0 += x0.x * wv.x + x0.y * wv.y + x0.z * wv.z + x0.w * wv.w;
            a1 += x1.x * wv.x + x1.y * wv.y + x1.z * wv.z + x1.w * wv.w;
            a2 += x2.x * wv.x + x2.y * wv.y + x2.z * wv.z + x2.w * wv.w;
            a3 += x3.x * wv.x + x3.y * wv.y + x3.z * wv.z + x3.w * wv.w;
        }
        float accs[4] = {a0, a1, a2, a3};
        #pragma unroll
        for (int j = 0; j < 4; ++j) {
            int n = nb + j;
            if (n >= N) break;
            float acc = accs[j];
            h[(size_t)n * 64 + lane] = f2bf(acc);
            float pa = acc * as, pr = acc * ad;
            #pragma unroll
            for (int off = 32; off > 0; off >>= 1) {
                pa += __shfl_down(pa, off);
                pr += __shfl_down(pr, off);
            }
            if (lane == 0) { al[n] = pa; ar[n] = pr; }
        }
    }
}

// ============================ CSR build (once) =============================
__global__ void csr_zero(int* __restrict__ deg, int* __restrict__ cursor, int N)
{
    int i = blockIdx.x * blockDim.x + threadIdx.x;
    if (i < N) { deg[i] = 0; cursor[i] = 0; }
}

__global__ void csr_hist(const int* __restrict__ dst, int* __restrict__ deg, int E)
{
    int i = blockIdx.x * blockDim.x + threadIdx.x;
    if (i < E) atomicAdd(&deg[dst[i]], 1);
}

__global__ void csr_scan1(const int* __restrict__ deg, int* __restrict__ incl,
                          int* __restrict__ part, int N)
{
    __shared__ int sb[2][256];
    int tid = threadIdx.x;
    int i = blockIdx.x * 256 + tid;
    int v = (i < N) ? deg[i] + 1 : 0;
    sb[0][tid] = v;
    __syncthreads();
    int cur = 0;
    #pragma unroll
    for (int off = 1; off < 256; off <<= 1) {
        int s = sb[cur][tid];
        if (tid >= off) s += sb[cur][tid - off];
        sb[cur ^ 1][tid] = s;
        cur ^= 1;
        __syncthreads();
    }
    if (i < N) incl[i] = sb[cur][tid];
    if (tid == 255) part[blockIdx.x] = sb[cur][255];
}

__global__ void csr_scan2(int* __restrict__ part, int NB)
{
    __shared__ int sb[2][256];
    int tid = threadIdx.x;
    int v = (tid < NB) ? part[tid] : 0;
    sb[0][tid] = v;
    __syncthreads();
    int cur = 0;
    #pragma unroll
    for (int off = 1; off < 256; off <<= 1) {
        int s = sb[cur][tid];
        if (tid >= off) s += sb[cur][tid - off];
        sb[cur ^ 1][tid] = s;
        cur ^= 1;
        __syncthreads();
    }
    if (tid < NB) part[tid] = sb[cur][tid] - v;   // exclusive
}

__global__ void csr_scan3(const int* __restrict__ deg, const int* __restrict__ incl,
                          const int* __restrict__ part, int* __restrict__ rowptr,
                          int N, int total)
{
    int i = blockIdx.x * blockDim.x + threadIdx.x;
    if (i < N)
        rowptr[i] = part[i >> 8] + incl[i] - (deg[i] + 1);
    if (i == 0) rowptr[N] = total;
}

__global__ void csr_scatter(const int* __restrict__ src, const int* __restrict__ dst,
                            const int* __restrict__ rowptr, int* __restrict__ cursor,
                            int* __restrict__ csr_src, int E, int N)
{
    int i = blockIdx.x * blockDim.x + threadIdx.x;
    if (i >= E + N) return;
    int s = (i < E) ? src[i] : (i - E);
    int d = (i < E) ? dst[i] : (i - E);
    int pos = atomicAdd(&cursor[d], 1);
    csr_src[rowptr[d] + pos] = s;
}

// ---- per-dst aggregation: softmax-weighted neighbor sum, fused finalize ----
// 16-lane group per dst (4 dst/wave -> 4x fewer waves than wave-per-dst).
// phase1: 16 edges/iter; phase2: 1 edge/iter x 4 ch/lane (8B loads, group
// covers 128B contiguous). No cross-group combine needed.
// Dual output: f32 seq (next lin layer) + bf16 seq (LSTM A-frags + jk).
__global__ __launch_bounds__(256) void agg_kernel(
    const int* __restrict__ rowptr, const int* __restrict__ csr_src,
    const float* __restrict__ al, const float* __restrict__ ar,
    const unsigned short* __restrict__ h, const float* __restrict__ b,
    float* __restrict__ outseq, unsigned short* __restrict__ outseq_bf, int N)
{
    int lane = threadIdx.x & 63;
    int w = threadIdx.x >> 6;
    int li = lane & 15, grp = lane >> 4;          // group = 1 dst
    int d = blockIdx.x * 16 + w * 4 + grp;
    if (d >= N) return;

    int rp0 = rowptr[d], rp1 = rowptr[d + 1];
    int degd = rp1 - rp0;
    float ard = ar[d];
    float den = 0.0f;
    float a0 = 0.f, a1 = 0.f, a2 = 0.f, a3 = 0.f;
    const int grpbase = grp << 4;

    for (int c0 = 0; c0 < degd; c0 += 16) {
        int ne = min(16, degd - c0);
        int s_l = 0;
        float ex_l = 0.0f;                        // stays 0 for li >= ne
        if (li < ne) {
            s_l = csr_src[rp0 + c0 + li];
            float e = al[s_l] + ard;
            e = (e >= 0.0f) ? e : 0.2f * e;
            ex_l = __expf(e);
        }
        float dsum = ex_l;                        // 16-lane reduce (in-group)
        dsum += __shfl_xor(dsum, 1);
        dsum += __shfl_xor(dsum, 2);
        dsum += __shfl_xor(dsum, 4);
        dsum += __shfl_xor(dsum, 8);
        den += dsum;
        #pragma unroll 4
        for (int e2 = 0; e2 < ne; ++e2) {
            int sl = grpbase + e2;                // absolute lane in wave
            float exb = __shfl(ex_l, sl);
            int sb = __shfl(s_l, sl);
            uint2 hv = *reinterpret_cast<const uint2*>(
                &h[(size_t)sb * 64 + li * 4]);
            a0 += exb * bf2f((unsigned short)(hv.x & 0xFFFFu));
            a1 += exb * bf2f((unsigned short)(hv.x >> 16));
            a2 += exb * bf2f((unsigned short)(hv.y & 0xFFFFu));
            a3 += exb * bf2f((unsigned short)(hv.y >> 16));
        }
    }
    float inv = rcp_f(den);
    int ch = li * 4;
    float4 v;
    v.x = fmaxf(fmaf(a0, inv, b[ch]),     0.0f);
    v.y = fmaxf(fmaf(a1, inv, b[ch + 1]), 0.0f);
    v.z = fmaxf(fmaf(a2, inv, b[ch + 2]), 0.0f);
    v.w = fmaxf(fmaf(a3, inv, b[ch + 3]), 0.0f);
    *reinterpret_cast<float4*>(&outseq[(size_t)d * 64 + ch]) = v;
    uint2 bb;
    bb.x = (unsigned int)f2bf(v.x) | ((unsigned int)f2bf(v.y) << 16);
    bb.y = (unsigned int)f2bf(v.z) | ((unsigned int)f2bf(v.w) << 16);
    *reinterpret_cast<uint2*>(&outseq_bf[(size_t)d * 64 + ch]) = bb;
}

// ---- LSTM weight prep: bf16, FRAGMENT-LANE-MAJOR order --------------------
// Per dir (61440 bf16): Wih frags f=(q*6+t6)*2+kc (48), Whh frags at +24576,
// f=(q*6+t6)*3+kc (72). Each frag = 512 bf16: [lane][slot], lane=(g<<4)|i16,
// value = W[j = q*96+t6*16+i16][k = kc*32+g*8+slot].
__global__ void prep_lstm(
    const float* __restrict__ WihF, const float* __restrict__ WhhF,
    const float* __restrict__ bihF, const float* __restrict__ bhhF,
    const float* __restrict__ WihB_, const float* __restrict__ WhhB_,
    const float* __restrict__ bihB_, const float* __restrict__ bhhB_,
    unsigned short* __restrict__ WB, float* __restrict__ bsum)
{
    int tid = blockIdx.x * blockDim.x + threadIdx.x;
    if (tid < 2 * 61440) {
        int dir = tid / 61440, rr = tid % 61440;
        const float* Wih = dir ? WihB_ : WihF;
        const float* Whh = dir ? WhhB_ : WhhF;
        float v;
        if (rr < 24576) {
            int f = rr >> 9, l = (rr >> 3) & 63, s = rr & 7;
            int kc = f & 1, qt = f >> 1;
            int q = qt / 6, t6 = qt % 6;
            int j = q * 96 + t6 * 16 + (l & 15);
            int k = kc * 32 + (l >> 4) * 8 + s;
            v = Wih[j * 64 + k];
        } else {
            int rr2 = rr - 24576;
            int f = rr2 >> 9, l = (rr2 >> 3) & 63, s = rr2 & 7;
            int kc = f % 3, qt = f / 3;
            int q = qt / 6, t6 = qt % 6;
            int j = q * 96 + t6 * 16 + (l & 15);
            int k = kc * 32 + (l >> 4) * 8 + s;
            v = Whh[j * 96 + k];
        }
        WB[tid] = f2bf(v);
    } else if (tid < 2 * 61440 + 2 * 384) {
        int q2 = tid - 2 * 61440;
        int dir = q2 / 384, j = q2 % 384;
        bsum[q2] = dir ? (bihB_[j] + bhhB_[j]) : (bihF[j] + bhhF[j]);
    }
}

// ---- fused BiLSTM (MFMA, LDS weights) + JK attention + out projection -----
// 512 threads = 8 waves, 128 nodes/block. Wave w owns nodes 16w..16w+15;
// c thread-private, hs rows wave-private -> no barriers in the recurrence.
// LDS (shorts): [0,61440) W frags (one dir: Wih 24576 | Whh 36864)
//               [61440,74752) hs, 128 rows stride 104
//               [74752,75520) logits (384 f32)
// = 151 KB -> 1 block/CU, 2 waves/SIMD. x A-frags: b128 loads from bf16 seq.
__global__ __launch_bounds__(512, 2) void lstm_kernel(
    const unsigned short* __restrict__ seq_bf,
    const unsigned short* __restrict__ WB,
    const float* __restrict__ bsum, const float* __restrict__ attW,
    const float* __restrict__ attb, const float* __restrict__ outW,
    const float* __restrict__ outb, float* __restrict__ out, int N)
{
    __shared__ __align__(16) unsigned short smem[75520];
    unsigned short* WL = smem;                           // 61440 shorts
    unsigned short* HS = smem + 61440;                   // 128*104 = 13312
    float* LG = reinterpret_cast<float*>(smem + 74752);  // 384 floats

    const int tid  = threadIdx.x;
    const int lane = tid & 63;
    const int w    = tid >> 6;          // 0..7
    const int i16  = lane & 15;
    const int g    = lane >> 4;
    const int n0   = blockIdx.x * 128;
    const int nodebase = 16 * w;
    const int myrow = nodebase + g * 4;

    float attb0 = attb[0];
    if (tid < 384) LG[tid] = attb0;

    for (int dir = 0; dir < 2; ++dir) {
        __syncthreads();   // prev dir's WL reads done / LG init visible
        {   // stage this dir's 120 KB of weight fragments (linear, b128)
            const f32x4* gsrc = reinterpret_cast<const f32x4*>(WB + dir * 61440);
            f32x4* ldst = reinterpret_cast<f32x4*>(WL);
            #pragma unroll
            for (int it = 0; it < 15; ++it)
                ldst[it * 512 + tid] = gsrc[it * 512 + tid];
        }
        // zero this wave's hs rows (wave-private, contiguous 16*104 shorts)
        {
            unsigned int* hz = reinterpret_cast<unsigned int*>(&HS[nodebase * 104]);
            for (int e2 = lane; e2 < 832; e2 += 64) hz[e2] = 0u;
        }
        const float* bs = bsum + dir * 384;
        const float* aw = attW + dir * 96;
        float bsr[24];
        #pragma unroll
        for (int t6 = 0; t6 < 6; ++t6)
            #pragma unroll
            for (int q = 0; q < 4; ++q)
                bsr[t6 * 4 + q] = bs[q * 96 + t6 * 16 + i16];
        float awr[6];
        #pragma unroll
        for (int t6 = 0; t6 < 6; ++t6) awr[t6] = aw[t6 * 16 + i16];
        float c[24];
        #pragma unroll
        for (int a = 0; a < 24; ++a) c[a] = 0.0f;
        __syncthreads();   // WL + hs visible

        for (int step = 0; step < 3; ++step) {
            int t = dir ? (2 - step) : step;

            // x A-frags: two b128 loads from bf16 seq (no conversion VALU)
            int nn = n0 + nodebase + i16;
            nn = (nn < N) ? nn : (N - 1);
            const unsigned short* xr = seq_bf + ((size_t)t * N + nn) * 64 + g * 8;
            bf16x8 ax0 = *reinterpret_cast<const bf16x8*>(xr);
            bf16x8 ax1 = *reinterpret_cast<const bf16x8*>(xr + 32);

            // h A-frags from LDS
            const unsigned short* hrow = &HS[(nodebase + i16) * 104];
            bf16x8 ah0 = *reinterpret_cast<const bf16x8*>(hrow + g * 8);
            bf16x8 ah1 = *reinterpret_cast<const bf16x8*>(hrow + 32 + g * 8);
            bf16x8 ah2 = *reinterpret_cast<const bf16x8*>(hrow + 64 + g * 8);
            const unsigned short* wbase = WL + lane * 8;

            float lp[4] = {0.0f, 0.0f, 0.0f, 0.0f};
            #pragma unroll
            for (int t6 = 0; t6 < 6; ++t6) {
                const int jb = t6 * 16 + i16;
                f32x4 acc4[4];
                #pragma unroll
                for (int q = 0; q < 4; ++q) {
                    float bv = bsr[t6 * 4 + q];
                    acc4[q] = (f32x4){bv, bv, bv, bv};
                }
                #pragma unroll
                for (int q = 0; q < 4; ++q) {
                    const int qt = q * 6 + t6;
                    const unsigned short* wih = wbase + (qt * 2) * 512;
                    const unsigned short* whh = wbase + 24576 + (qt * 3) * 512;
                    acc4[q] = __builtin_amdgcn_mfma_f32_16x16x32_bf16(
                        ax0, *reinterpret_cast<const bf16x8*>(wih), acc4[q], 0, 0, 0);
                    acc4[q] = __builtin_amdgcn_mfma_f32_16x16x32_bf16(
                        ax1, *reinterpret_cast<const bf16x8*>(wih + 512), acc4[q], 0, 0, 0);
                    acc4[q] = __builtin_amdgcn_mfma_f32_16x16x32_bf16(
                        ah0, *reinterpret_cast<const bf16x8*>(whh), acc4[q], 0, 0, 0);
                    acc4[q] = __builtin_amdgcn_mfma_f32_16x16x32_bf16(
                        ah1, *reinterpret_cast<const bf16x8*>(whh + 512), acc4[q], 0, 0, 0);
                    acc4[q] = __builtin_amdgcn_mfma_f32_16x16x32_bf16(
                        ah2, *reinterpret_cast<const bf16x8*>(whh + 1024), acc4[q], 0, 0, 0);
                }
                #pragma unroll
                for (int reg = 0; reg < 4; ++reg) {
                    float ii = acc4[0][reg];
                    float ff = acc4[1][reg];
                    float gg = acc4[2][reg];
                    float oo = acc4[3][reg];
                    float cn = sigmoid_f(ff) * c[t6 * 4 + reg]
                             + sigmoid_f(ii) * tanh_f(gg);
                    c[t6 * 4 + reg] = cn;
                    float hn = sigmoid_f(oo) * tanh_f(cn);
                    HS[(myrow + reg) * 104 + jb] = f2bf(hn);
                    lp[reg] += hn * awr[t6];
                }
            }
            #pragma unroll
            for (int reg = 0; reg < 4; ++reg) {
                float v = lp[reg];
                v += __shfl_xor(v, 1);
                v += __shfl_xor(v, 2);
                v += __shfl_xor(v, 4);
                v += __shfl_xor(v, 8);
                if (i16 == 0) LG[t * 128 + myrow + reg] += v;
            }
        }
    }
    __syncthreads();

    // alpha = softmax over the 3 layers (hs dead -> reuse as alpha buffer)
    float* alphaF = reinterpret_cast<float*>(HS);
    if (tid < 128) {
        float l0 = LG[tid], l1 = LG[128 + tid], l2 = LG[256 + tid];
        float mx = fmaxf(fmaxf(l0, l1), l2);
        float e0 = __expf(l0 - mx), e1 = __expf(l1 - mx), e2 = __expf(l2 - mx);
        float inv = rcp_f(e0 + e1 + e2);
        alphaF[tid] = e0 * inv; alphaF[128 + tid] = e1 * inv;
        alphaF[256 + tid] = e2 * inv;
    }
    __syncthreads();

    // agg[n][k] = sum_t alpha[t][n] * seq_bf[t][n][k]  (overwrites W region)
    float* aggF = reinterpret_cast<float*>(WL);     // stride 68 floats
    for (int idx = tid; idx < 128 * 64; idx += 512) {
        int r = idx >> 6, k = idx & 63;
        int n = n0 + r;
        float v = 0.0f;
        if (n < N) {
            float a0 = alphaF[r], a1 = alphaF[128 + r], a2 = alphaF[256 + r];
            v = a0 * bf2f(seq_bf[((size_t)n) * 64 + k])
              + a1 * bf2f(seq_bf[((size_t)N + n) * 64 + k])
              + a2 * bf2f(seq_bf[((size_t)2 * N + n) * 64 + k]);
        }
        aggF[r * 68 + k] = v;
    }
    __syncthreads();

    // out[n][j] = agg[n] . outW[j] + outb[j]; outW row held in 64 VGPRs
    f32x4 ow[16];
    #pragma unroll
    for (int kk = 0; kk < 16; ++kk)
        ow[kk] = *reinterpret_cast<const f32x4*>(&outW[(size_t)lane * 64 + kk * 4]);
    float ob = outb[lane];
    for (int r = w; r < 128; r += 8) {
        int n = n0 + r;
        if (n >= N) break;
        float a = ob;
        #pragma unroll
        for (int kk = 0; kk < 16; ++kk) {
            f32x4 av = *reinterpret_cast<const f32x4*>(&aggF[r * 68 + kk * 4]);
            a += ow[kk].x * av.x + ow[kk].y * av.y
               + ow[kk].z * av.z + ow[kk].w * av.w;
        }
        out[(size_t)n * 64 + lane] = a;
    }
}

// ---------------------------------------------------------------------------
extern "C" void kernel_launch(void* const* d_in, const int* in_sizes, int n_in,
                              void* d_out, int out_size, void* d_ws, size_t ws_size,
                              hipStream_t stream)
{
    const float* x    = (const float*)d_in[0];
    const int*   ei   = (const int*)d_in[1];
    const float* convW[3]  = {(const float*)d_in[2], (const float*)d_in[6],  (const float*)d_in[10]};
    const float* convAs[3] = {(const float*)d_in[3], (const float*)d_in[7],  (const float*)d_in[11]};
    const float* convAd[3] = {(const float*)d_in[4], (const float*)d_in[8],  (const float*)d_in[12]};
    const float* convB[3]  = {(const float*)d_in[5], (const float*)d_in[9],  (const float*)d_in[13]};
    const float* WihF = (const float*)d_in[14];
    const float* WhhF = (const float*)d_in[15];
    const float* bihF = (const float*)d_in[16];
    const float* bhhF = (const float*)d_in[17];
    const float* WihB = (const float*)d_in[18];
    const float* WhhB = (const float*)d_in[19];
    const float* bihB = (const float*)d_in[20];
    const float* bhhB = (const float*)d_in[21];
    const float* attW = (const float*)d_in[22];
    const float* attb = (const float*)d_in[23];
    const float* outW = (const float*)d_in[24];
    const float* outb = (const float*)d_in[25];

    int N = in_sizes[0] / 128;
    int E = in_sizes[1] / 2;
    const int* src = ei;
    const int* dst = ei + E;
    int total = E + N;

    float* w = (float*)d_ws;
    float* seq  = w;  w += (size_t)3 * N * 64;
    unsigned short* h_bf = (unsigned short*)w;  w += (size_t)N * 32;   // N*64 bf16
    float* al   = w;  w += N;
    float* ar   = w;  w += N;
    float* bsum = w;  w += 768;
    unsigned short* WB = (unsigned short*)w;  w += 61440;   // 122880 bf16
    unsigned short* seq_bf = (unsigned short*)w;  w += (size_t)3 * N * 32;  // bf16
    int* deg     = (int*)w;        w += N;
    int* cursor  = (int*)w;        w += N;
    int* rowptr  = (int*)w;        w += (N + 1);
    int* incl    = (int*)w;        w += N;
    int* part    = (int*)w;        w += 256;
    int* csr_src = (int*)w;        w += total;

    int NB = (N + 255) / 256;

    // CSR build (graph is layer-invariant)
    csr_zero<<<NB, 256, 0, stream>>>(deg, cursor, N);
    csr_hist<<<(E + 255) / 256, 256, 0, stream>>>(dst, deg, E);
    csr_scan1<<<NB, 256, 0, stream>>>(deg, incl, part, N);
    csr_scan2<<<1, 256, 0, stream>>>(part, NB);
    csr_scan3<<<NB, 256, 0, stream>>>(deg, incl, part, rowptr, N, total);
    csr_scatter<<<(total + 255) / 256, 256, 0, stream>>>(src, dst, rowptr, cursor,
                                                         csr_src, E, N);

    prep_lstm<<<(2 * 61440 + 768 + 255) / 256, 256, 0, stream>>>(
        WihF, WhhF, bihF, bhhF, WihB, WhhB, bihB, bhhB, WB, bsum);

    for (int l = 0; l < 3; ++l) {
        const float* in = (l == 0) ? x : seq + (size_t)(l - 1) * N * 64;
        if (l == 0)
            lin_kernel<128><<<2048, 256, 0, stream>>>(in, convW[l], convAs[l], convAd[l],
                                                      h_bf, al, ar, N);
        else
            lin_kernel<64><<<2048, 256, 0, stream>>>(in, convW[l], convAs[l], convAd[l],
                                                     h_bf, al, ar, N);
        agg_kernel<<<(N + 15) / 16, 256, 0, stream>>>(rowptr, csr_src, al, ar, h_bf,
                                                      convB[l], seq + (size_t)l * N * 64,
                                                      seq_bf + (size_t)l * N * 64, N);
    }

    lstm_kernel<<<(N + 127) / 128, 512, 0, stream>>>(seq_bf, WB, bsum, attW, attb,
                                                     outW, outb, (float*)d_out, N);
}